// Round 6
// baseline (2837.275 us; speedup 1.0000x reference)
//
#include <hip/hip_runtime.h>
#include <hip/hip_fp16.h>
#include <math.h>

// Liquid-network recurrence via MFMA matvec. One batch row per CU.
// grid=256, block=256 (4 waves, 1 wave/SIMD -> 512 unified regs/thread).
// Wave w owns output cols [128w,128w+128) = 8 N-tiles x 16 K-tiles of
// v_mfma_f32_16x16x32_f16 with M=1 (A = h row, broadcast k-slices).
//   kt 0..11 -> register-resident B-frags (96 tiles, 384 regs, arch+acc)
//   kt 12..15 -> LDS-streamed B-frags (32 tiles/wave, 128 KB)
// Every lane's A-frag = h[kt*32+(l>>4)*8 .. +8] (row-independent), so all
// 16 C rows equal rec; row 0 (lanes 0-15, reg 0) is extracted.
// Each thread owns 2 hidden columns (t, t+256) for LN/update.

#define HID    512
#define NSTEP  1024
#define BLK    256
#define KT_REG 12
#define NT     8

typedef _Float16 f16x8 __attribute__((ext_vector_type(8)));
typedef float    f32x4 __attribute__((ext_vector_type(4)));

// LDS byte offsets
#define OFF_WS   0                  // 4 waves * 32 tiles * 1024 B = 131072
#define OFF_HB   131072             // 2 * 512 halves = 2048
#define OFF_REC  133120             // 512 f32 = 2048
#define OFF_XLS  135168             // 2048 f32 = 8192
#define OFF_RED  143360             // 16 f32 = 64
#define OFF_HNA  143424             // 512 f32 = 2048
#define OFF_PSUM 145472             // 160 f32 = 640
#define SMEM_BYTES 146112

union FU { f16x8 f; uint4 u; };

template <int CTRL>
__device__ __forceinline__ float dpp_f(float v) {
    int r = __builtin_amdgcn_update_dpp(0, __builtin_bit_cast(int, v),
                                        CTRL, 0xF, 0xF, true);
    return __builtin_bit_cast(float, r);
}
__device__ __forceinline__ float swz16_f(float v) {
    int r = __builtin_amdgcn_ds_swizzle(__builtin_bit_cast(int, v), 0x401F); // xor16
    return __builtin_bit_cast(float, r);
}
__device__ __forceinline__ float tanh_fast(float y) {
    float e = __expf(2.0f * y);
    return 1.0f - 2.0f * __builtin_amdgcn_rcpf(e + 1.0f);
}

// load one B fragment: elements e=0..7 <-> rows base_row+e, fixed column
__device__ __forceinline__ f16x8 load_bfrag(const float* __restrict__ w,
                                            int base_row, int col) {
    const float* p = w + (size_t)base_row * HID + col;
    f16x8 f;
    #pragma unroll
    for (int e = 0; e < 8; ++e) f[e] = (_Float16)p[e * HID];
    return f;
}

extern "C" __global__ void __launch_bounds__(BLK, 1)
__attribute__((amdgpu_waves_per_eu(1, 1)))
liquid_kernel(const float* __restrict__ x, const float* __restrict__ ctx,
              const float* __restrict__ ce_w1, const float* __restrict__ ce_b1,
              const float* __restrict__ ce_w2, const float* __restrict__ ce_b2,
              const float* __restrict__ in_w, const float* __restrict__ in_b,
              const float* __restrict__ rec_w, const float* __restrict__ tau,
              const float* __restrict__ intra_g, const float* __restrict__ intra_b,
              const float* __restrict__ norm_g, const float* __restrict__ norm_b,
              const float* __restrict__ head_w, const float* __restrict__ head_b,
              float* __restrict__ out)
{
    extern __shared__ char smem[];
    float*  recL = (float*)(smem + OFF_REC);
    float*  xls  = (float*)(smem + OFF_XLS);
    float*  redS = (float*)(smem + OFF_RED);
    float*  hnA  = (float*)(smem + OFF_HNA);
    float*  psum = (float*)(smem + OFF_PSUM);
    __half* hb0  = (__half*)(smem + OFF_HB);
    __half* hb1  = (__half*)(smem + OFF_HB + 1024);

    const int b   = blockIdx.x;
    const int t   = threadIdx.x;
    const int l   = t & 63;        // lane
    const int w   = t >> 6;        // wave 0..3
    const int lHi = l >> 4;        // k-group 0..3
    const int lLo = l & 15;        // column-within-tile
    const int cb  = w * 128;       // wave column base

    // ---- stage x[b] (1024 x 2 fp32 = 8 KB), coalesced ----
    const float* xb = x + (size_t)b * (NSTEP * 2);
    #pragma unroll
    for (int q = 0; q < 8; ++q) xls[t + q * BLK] = xb[t + q * BLK];

    // ---- per-thread params for cols c0=t, c1=t+256 ----
    const int c0 = t, c1 = t + 256;
    const float g0 = intra_g[c0], g1 = intra_g[c1];
    const float bb0 = intra_b[c0], bb1 = intra_b[c1];
    const float iw00 = in_w[c0], iw01 = in_w[c1];
    const float iw10 = in_w[HID + c0], iw11 = in_w[HID + c1];
    const float ib0 = in_b[c0], ib1 = in_b[c1];
    const float tj0 = tau[c0], tj1 = tau[c1];
    const float it0 = 1.0f / ((tj0 > 30.f) ? tj0 : log1pf(__expf(tj0)));
    const float it1 = 1.0f / ((tj1 > 30.f) ? tj1 : log1pf(__expf(tj1)));

    // ---- h0 = tanh(relu(ctx@ce_w1+b1)@ce_w2+b2) for both cols ----
    float t1[32];
    #pragma unroll
    for (int k = 0; k < 32; ++k) {
        float s = ce_b1[k];
        #pragma unroll
        for (int i = 0; i < 6; ++i) s += ctx[b * 6 + i] * ce_w1[i * 32 + k];
        t1[k] = fmaxf(s, 0.f);
    }
    float s00 = ce_b2[c0], s01 = ce_b2[c1];
    #pragma unroll
    for (int k = 0; k < 32; ++k) {
        s00 += t1[k] * ce_w2[k * HID + c0];
        s01 += t1[k] * ce_w2[k * HID + c1];
    }
    float h0 = tanh_fast(s00);
    float h1 = tanh_fast(s01);

    // ---- register-resident B fragments: kt 0..11, nt 0..7 ----
    f16x8 bR[KT_REG * NT];
    #pragma unroll
    for (int kt = 0; kt < KT_REG; ++kt) {
        #pragma unroll
        for (int nt = 0; nt < NT; ++nt)
            bR[kt * NT + nt] = load_bfrag(rec_w, kt * 32 + lHi * 8,
                                          cb + nt * 16 + lLo);
    }
    // ---- LDS-streamed B fragments: kt 12..15 ----
    char* wbase = smem + OFF_WS + (size_t)w * 32768 + (size_t)l * 16;
    #pragma unroll
    for (int kt2 = 0; kt2 < 4; ++kt2) {
        #pragma unroll
        for (int nt = 0; nt < NT; ++nt) {
            FU fu;
            fu.f = load_bfrag(rec_w, (KT_REG + kt2) * 32 + lHi * 8,
                              cb + nt * 16 + lLo);
            *(uint4*)(wbase + ((kt2 * NT + nt) << 10)) = fu.u;
        }
    }

    // ---- write h0 into buffer 0 ----
    hb0[c0] = __float2half_rn(h0);
    hb0[c1] = __float2half_rn(h1);
    __syncthreads();

    __half* hR = hb0;
    __half* hW = hb1;

    for (int step = 0; step < NSTEP; ++step) {
        // ---- MFMA matvec: rec = h @ W ----
        const uint4* hv4 = (const uint4*)hR;   // 64 x uint4 = 512 halves
        f32x4 c[NT];
        #pragma unroll
        for (int nt = 0; nt < NT; ++nt) c[nt] = (f32x4){0.f, 0.f, 0.f, 0.f};

        #pragma unroll
        for (int kt = 0; kt < KT_REG; ++kt) {
            FU au; au.u = hv4[kt * 4 + lHi];
            #pragma unroll
            for (int nt = 0; nt < NT; ++nt)
                c[nt] = __builtin_amdgcn_mfma_f32_16x16x32_f16(
                            au.f, bR[kt * NT + nt], c[nt], 0, 0, 0);
        }
        #pragma unroll
        for (int kt2 = 0; kt2 < 4; ++kt2) {
            FU au; au.u = hv4[(KT_REG + kt2) * 4 + lHi];
            #pragma unroll
            for (int nt = 0; nt < NT; ++nt) {
                FU bu; bu.u = *(const uint4*)(wbase + ((kt2 * NT + nt) << 10));
                c[nt] = __builtin_amdgcn_mfma_f32_16x16x32_f16(
                            au.f, bu.f, c[nt], 0, 0, 0);
            }
        }

        // ---- extract rec row 0: lanes 0-15, reg 0 ----
        if (l < 16) {
            #pragma unroll
            for (int nt = 0; nt < NT; ++nt)
                recL[cb + nt * 16 + l] = c[nt][0];
        }
        __syncthreads();   // B: rec ready

        // ---- LN + update for cols c0, c1 ----
        float2 xv = ((const float2*)xls)[step];
        float v0 = recL[c0] + fmaf(xv.x, iw00, fmaf(xv.y, iw10, ib0));
        float v1 = recL[c1] + fmaf(xv.x, iw01, fmaf(xv.y, iw11, ib1));

        float s1 = v0 + v1, sq = v0 * v0 + v1 * v1;
        s1 += dpp_f<0xB1>(s1);  sq += dpp_f<0xB1>(sq);
        s1 += dpp_f<0x4E>(s1);  sq += dpp_f<0x4E>(sq);
        s1 += dpp_f<0x141>(s1); sq += dpp_f<0x141>(sq);
        s1 += dpp_f<0x140>(s1); sq += dpp_f<0x140>(sq);
        s1 += swz16_f(s1);      sq += swz16_f(sq);
        s1 += __shfl_xor(s1, 32); sq += __shfl_xor(sq, 32);
        if (l == 0) { redS[w] = s1; redS[4 + w] = sq; }
        __syncthreads();   // C: stats ready

        const float4 r0 = *(const float4*)redS;
        const float4 r1 = *(const float4*)(redS + 4);
        float S1 = (r0.x + r0.y) + (r0.z + r0.w);
        float S2 = (r1.x + r1.y) + (r1.z + r1.w);
        float mu  = S1 * (1.0f / HID);
        float var = S2 * (1.0f / HID) - mu * mu;
        float rs  = rsqrtf(var + 1e-5f);

        float f0 = tanh_fast((v0 - mu) * rs * g0 + bb0);
        float f1 = tanh_fast((v1 - mu) * rs * g1 + bb1);
        h0 = fminf(fmaxf(h0 + (f0 - h0 * it0) * 0.1f, -10.f), 10.f);
        h1 = fminf(fmaxf(h1 + (f1 - h1 * it1) * 0.1f, -10.f), 10.f);
        hW[c0] = __float2half_rn(h0);
        hW[c1] = __float2half_rn(h1);
        __syncthreads();   // A: h ready
        __half* tm = hR; hR = hW; hW = tm;
    }

    // ---- final layernorm over 512 cols ----
    float s1 = h0 + h1, sq = h0 * h0 + h1 * h1;
    s1 += dpp_f<0xB1>(s1);  sq += dpp_f<0xB1>(sq);
    s1 += dpp_f<0x4E>(s1);  sq += dpp_f<0x4E>(sq);
    s1 += dpp_f<0x141>(s1); sq += dpp_f<0x141>(sq);
    s1 += dpp_f<0x140>(s1); sq += dpp_f<0x140>(sq);
    s1 += swz16_f(s1);      sq += swz16_f(sq);
    s1 += __shfl_xor(s1, 32); sq += __shfl_xor(sq, 32);
    if (l == 0) { redS[w] = s1; redS[4 + w] = sq; }
    __syncthreads();
    {
        const float4 r0 = *(const float4*)redS;
        const float4 r1 = *(const float4*)(redS + 4);
        float S1 = (r0.x + r0.y) + (r0.z + r0.w);
        float S2 = (r1.x + r1.y) + (r1.z + r1.w);
        float mu  = S1 * (1.0f / HID);
        float var = S2 * (1.0f / HID) - mu * mu;
        float rs  = rsqrtf(var + 1e-5f);
        hnA[c0] = (h0 - mu) * rs * norm_g[c0] + norm_b[c0];
        hnA[c1] = (h1 - mu) * rs * norm_g[c1] + norm_b[c1];
    }
    __syncthreads();

    // ---- heads: out[b, a] = hn . head_w[:, a] + head_b[a] ----
    if (t < 160) {
        int a = t >> 3, part = t & 7;
        float s = 0.f;
        #pragma unroll 8
        for (int q = 0; q < 64; ++q) {
            int row = part * 64 + q;
            s += hnA[row] * head_w[row * 20 + a];
        }
        psum[a * 8 + part] = s;
    }
    __syncthreads();
    if (t < 20) {
        float s = head_b[t];
        #pragma unroll
        for (int q = 0; q < 8; ++q) s += psum[t * 8 + q];
        out[b * 20 + t] = s;
    }
}

extern "C" void kernel_launch(void* const* d_in, const int* in_sizes, int n_in,
                              void* d_out, int out_size, void* d_ws, size_t ws_size,
                              hipStream_t stream) {
    const float* x       = (const float*)d_in[0];
    const float* ctx     = (const float*)d_in[1];
    const float* ce_w1   = (const float*)d_in[2];
    const float* ce_b1   = (const float*)d_in[3];
    const float* ce_w2   = (const float*)d_in[4];
    const float* ce_b2   = (const float*)d_in[5];
    const float* in_w    = (const float*)d_in[6];
    const float* in_b    = (const float*)d_in[7];
    const float* rec_w   = (const float*)d_in[8];
    const float* tau     = (const float*)d_in[9];
    const float* intra_g = (const float*)d_in[10];
    const float* intra_b = (const float*)d_in[11];
    const float* norm_g  = (const float*)d_in[12];
    const float* norm_b  = (const float*)d_in[13];
    const float* head_w  = (const float*)d_in[14];
    const float* head_b  = (const float*)d_in[15];
    float* outp = (float*)d_out;

    (void)d_ws; (void)ws_size; (void)n_in; (void)in_sizes; (void)out_size;

    // opt-in to >64KB dynamic LDS (160 KB/CU on gfx950); host-side, capture-safe
    hipFuncSetAttribute((const void*)liquid_kernel,
                        hipFuncAttributeMaxDynamicSharedMemorySize, SMEM_BYTES);

    liquid_kernel<<<dim3(256), dim3(BLK), SMEM_BYTES, stream>>>(
        x, ctx, ce_w1, ce_b1, ce_w2, ce_b2, in_w, in_b, rec_w, tau,
        intra_g, intra_b, norm_g, norm_b, head_w, head_b, outp);
}